// Round 1
// baseline (122.530 us; speedup 1.0000x reference)
//
#include <hip/hip_runtime.h>
#include <math.h>

#define DIM 4096
#define NQ 12

// LDS bank-conflict swizzle: spreads owned-bit strides across banks.
// Verified: write/read patterns for ownerships A (bits 8-11), B (bits 4-7),
// C (bits 0-3) all land at <=2 lanes/bank (2-way is free on CDNA4).
__device__ __forceinline__ int phys_idx(int i){
  return i ^ ((i >> 4) & 15) ^ (((i >> 8) & 1) << 4);
}

// CNOT ring: CNOT(0,1),CNOT(1,2),...,CNOT(10,11),CNOT(11,0).
// Wire w <-> bit position (11-w) (wire 0 is MSB).
// Gather map g: new[i] = old[g(i)]  (apply involutions in REVERSE gate order)
__device__ __forceinline__ int cnot_gather(int i){
  int j = i;
  j ^= (j & 1) << 11;                 // CNOT(11,0): control bit0 -> target bit11
#pragma unroll
  for (int q = 10; q >= 0; --q){      // CNOT(q,q+1): control bit(11-q) -> target bit(10-q)
    int pc = 11 - q, pt = 10 - q;
    j ^= ((j >> pc) & 1) << pt;
  }
  return j;
}

// Forward index map: amplitude at index i ends up at index cnot_forward(i).
__device__ __forceinline__ int cnot_forward(int i){
  int j = i;
#pragma unroll
  for (int q = 0; q <= 10; ++q){
    int pc = 11 - q, pt = 10 - q;
    j ^= ((j >> pc) & 1) << pt;
  }
  j ^= (j & 1) << 11;
  return j;
}

// Apply a fused 2x2 complex gate to register-resident state on owned bit J.
// u layout: {u00.re,u00.im,u01.re,u01.im,u10.re,u10.im,u11.re,u11.im}
template<int J>
__device__ __forceinline__ void gate_on_bit(float2 (&s)[16], const float* __restrict__ u){
  const float u00x=u[0], u00y=u[1], u01x=u[2], u01y=u[3];
  const float u10x=u[4], u10y=u[5], u11x=u[6], u11y=u[7];
#pragma unroll
  for (int k = 0; k < 16; ++k){
    if (k & (1 << J)) continue;       // compile-time folded (k, J constants)
    const int k1 = k | (1 << J);
    const float ax = s[k].x, ay = s[k].y, bx = s[k1].x, by = s[k1].y;
    s[k].x  = u00x*ax - u00y*ay + u01x*bx - u01y*by;
    s[k].y  = u00x*ay + u00y*ax + u01x*by + u01y*bx;
    s[k1].x = u10x*ax - u10y*ay + u11x*bx - u11y*by;
    s[k1].y = u10x*ay + u10y*ax + u11x*by + u11y*bx;
  }
}

// Precompute 24 fused U = Rz*Ry*Rx matrices (layer-major, qubit-minor).
__global__ __launch_bounds__(64)
void prep_gates(const float* __restrict__ w, float* __restrict__ U){
  const int t = threadIdx.x;
  if (t >= 24) return;
  const int l = t / 12, q = t % 12;
  const float ax = 0.5f * w[l*36 + q*3 + 0];
  const float ay = 0.5f * w[l*36 + q*3 + 1];
  const float az = 0.5f * w[l*36 + q*3 + 2];
  const float ca = cosf(ax), sa = sinf(ax);
  const float cb = cosf(ay), sb = sinf(ay);
  const float cc = cosf(az), sc = sinf(az);
  // M = Ry*Rx
  const float m00x =  cb*ca, m00y =  sb*sa;
  const float m01x = -sb*ca, m01y = -cb*sa;
  const float m10x =  sb*ca, m10y = -cb*sa;
  const float m11x =  cb*ca, m11y = -sb*sa;
  float* o = U + t*8;
  // row0 *= e^{-i az} = (cc - i sc);  row1 *= e^{+i az} = (cc + i sc)
  o[0] = cc*m00x + sc*m00y;  o[1] = cc*m00y - sc*m00x;
  o[2] = cc*m01x + sc*m01y;  o[3] = cc*m01y - sc*m01x;
  o[4] = cc*m10x - sc*m10y;  o[5] = cc*m10y + sc*m10x;
  o[6] = cc*m11x - sc*m11y;  o[7] = cc*m11y + sc*m11x;
}

__global__ __launch_bounds__(256)
void qsim_kernel(const float* __restrict__ x, const float* __restrict__ U,
                 float* __restrict__ out){
  __shared__ float re_s[DIM];
  __shared__ float im_s[DIM];
  const int tid = threadIdx.x;
  const int b   = blockIdx.x;

  // ---- broadcast per-sample encoding angles (cos/sin of x*pi/2) ----
  if (tid < NQ){
    const float a = x[b*NQ + tid] * 1.5707963267948966f;
    re_s[tid] = cosf(a);
    im_s[tid] = sinf(a);
  }
  __syncthreads();
  float cw[NQ], sw[NQ];
#pragma unroll
  for (int w = 0; w < NQ; ++w){ cw[w] = re_s[w]; sw[w] = im_s[w]; }
  __syncthreads();   // all reads done before state writes reuse this LDS

  // ---- init product state, ownership A: i = tid + 256*k (bits 8-11 = k) ----
  float2 s[16];
  float base = 1.f;
#pragma unroll
  for (int p = 0; p < 8; ++p) base *= ((tid >> p) & 1) ? sw[11-p] : cw[11-p];
#pragma unroll
  for (int k = 0; k < 16; ++k){
    float amp = base;
#pragma unroll
    for (int p = 8; p < 12; ++p) amp *= ((k >> (p-8)) & 1) ? sw[11-p] : cw[11-p];
    s[k] = make_float2(amp, 0.f);
  }

  // ================= layer 0 =================
  // ownership A: reg bit j <-> bit pos 8+j <-> wire 3-j
  gate_on_bit<0>(s, U + (0*12 + 3)*8);
  gate_on_bit<1>(s, U + (0*12 + 2)*8);
  gate_on_bit<2>(s, U + (0*12 + 1)*8);
  gate_on_bit<3>(s, U + (0*12 + 0)*8);
#pragma unroll
  for (int k = 0; k < 16; ++k){       // write A
    const int ph = phys_idx(tid + (k << 8));
    re_s[ph] = s[k].x; im_s[ph] = s[k].y;
  }
  __syncthreads();
#pragma unroll
  for (int k = 0; k < 16; ++k){       // read B: bits 4-7 = k
    const int ph = phys_idx((tid & 15) | (k << 4) | ((tid >> 4) << 8));
    s[k] = make_float2(re_s[ph], im_s[ph]);
  }
  // ownership B: reg bit j <-> pos 4+j <-> wire 7-j
  gate_on_bit<0>(s, U + (0*12 + 7)*8);
  gate_on_bit<1>(s, U + (0*12 + 6)*8);
  gate_on_bit<2>(s, U + (0*12 + 5)*8);
  gate_on_bit<3>(s, U + (0*12 + 4)*8);
#pragma unroll
  for (int k = 0; k < 16; ++k){       // write B (same slots just read -> no sync needed)
    const int ph = phys_idx((tid & 15) | (k << 4) | ((tid >> 4) << 8));
    re_s[ph] = s[k].x; im_s[ph] = s[k].y;
  }
  __syncthreads();
#pragma unroll
  for (int k = 0; k < 16; ++k){       // read C: bits 0-3 = k
    const int ph = phys_idx(k | (tid << 4));
    s[k] = make_float2(re_s[ph], im_s[ph]);
  }
  // ownership C: reg bit j <-> pos j <-> wire 11-j
  gate_on_bit<0>(s, U + (0*12 + 11)*8);
  gate_on_bit<1>(s, U + (0*12 + 10)*8);
  gate_on_bit<2>(s, U + (0*12 +  9)*8);
  gate_on_bit<3>(s, U + (0*12 +  8)*8);
#pragma unroll
  for (int k = 0; k < 16; ++k){       // write C
    const int ph = phys_idx(k | (tid << 4));
    re_s[ph] = s[k].x; im_s[ph] = s[k].y;
  }
  __syncthreads();

  // ================= layer 1 =================
  // CNOT ring of layer 0 folded into this gather; read ownership A
#pragma unroll
  for (int k = 0; k < 16; ++k){
    const int ph = phys_idx(cnot_gather(tid + (k << 8)));
    s[k] = make_float2(re_s[ph], im_s[ph]);
  }
  gate_on_bit<0>(s, U + (1*12 + 3)*8);
  gate_on_bit<1>(s, U + (1*12 + 2)*8);
  gate_on_bit<2>(s, U + (1*12 + 1)*8);
  gate_on_bit<3>(s, U + (1*12 + 0)*8);
  __syncthreads();   // gather reads (scattered) must finish before A-writes
#pragma unroll
  for (int k = 0; k < 16; ++k){       // write A
    const int ph = phys_idx(tid + (k << 8));
    re_s[ph] = s[k].x; im_s[ph] = s[k].y;
  }
  __syncthreads();
#pragma unroll
  for (int k = 0; k < 16; ++k){       // read B
    const int ph = phys_idx((tid & 15) | (k << 4) | ((tid >> 4) << 8));
    s[k] = make_float2(re_s[ph], im_s[ph]);
  }
  gate_on_bit<0>(s, U + (1*12 + 7)*8);
  gate_on_bit<1>(s, U + (1*12 + 6)*8);
  gate_on_bit<2>(s, U + (1*12 + 5)*8);
  gate_on_bit<3>(s, U + (1*12 + 4)*8);
#pragma unroll
  for (int k = 0; k < 16; ++k){       // write B
    const int ph = phys_idx((tid & 15) | (k << 4) | ((tid >> 4) << 8));
    re_s[ph] = s[k].x; im_s[ph] = s[k].y;
  }
  __syncthreads();
#pragma unroll
  for (int k = 0; k < 16; ++k){       // read C
    const int ph = phys_idx(k | (tid << 4));
    s[k] = make_float2(re_s[ph], im_s[ph]);
  }
  gate_on_bit<0>(s, U + (1*12 + 11)*8);
  gate_on_bit<1>(s, U + (1*12 + 10)*8);
  gate_on_bit<2>(s, U + (1*12 +  9)*8);
  gate_on_bit<3>(s, U + (1*12 +  8)*8);

  // ---- output: layer-1 CNOT ring folded into index remap; <Z_w> accumulation ----
  float acc[NQ];
#pragma unroll
  for (int w = 0; w < NQ; ++w) acc[w] = 0.f;
#pragma unroll
  for (int k = 0; k < 16; ++k){
    const int j = cnot_forward(k | (tid << 4));
    const float p2 = s[k].x*s[k].x + s[k].y*s[k].y;
#pragma unroll
    for (int w = 0; w < NQ; ++w)
      acc[w] += ((j >> (11 - w)) & 1) ? -p2 : p2;
  }
  __syncthreads();   // all state reads done; safe to reuse re_s for reduction

  // wave reduce (64-lane) then cross-wave via LDS
#pragma unroll
  for (int off = 32; off > 0; off >>= 1)
#pragma unroll
    for (int w = 0; w < NQ; ++w)
      acc[w] += __shfl_down(acc[w], off, 64);
  const int lane = tid & 63, wid = tid >> 6;
  if (lane == 0){
#pragma unroll
    for (int w = 0; w < NQ; ++w) re_s[wid*NQ + w] = acc[w];
  }
  __syncthreads();
  if (tid < NQ)
    out[b*NQ + tid] = re_s[tid] + re_s[NQ + tid] + re_s[2*NQ + tid] + re_s[3*NQ + tid];
}

extern "C" void kernel_launch(void* const* d_in, const int* in_sizes, int n_in,
                              void* d_out, int out_size, void* d_ws, size_t ws_size,
                              hipStream_t stream){
  const float* x = (const float*)d_in[0];
  const float* w = (const float*)d_in[1];
  float* out = (float*)d_out;
  float* U   = (float*)d_ws;          // 24 gates * 8 floats = 768 B
  const int B = in_sizes[0] / NQ;     // 2048

  prep_gates<<<1, 64, 0, stream>>>(w, U);
  qsim_kernel<<<B, 256, 0, stream>>>(x, U, out);
}

// Round 2
// 102.459 us; speedup vs baseline: 1.1959x; 1.1959x over previous
//
#include <hip/hip_runtime.h>
#include <math.h>

#define NQ 12
#define DIM 4096

// ---- GF(2)-linear index maps ----------------------------------------------
// LDS bank-swizzle (bijective, linear over GF(2))
__device__ __forceinline__ int physv(int i){ return i ^ ((i>>4)&15) ^ (((i>>8)&1)<<4); }
__host__ __device__ constexpr int physc(int i){ return i ^ ((i>>4)&15) ^ (((i>>8)&1)<<4); }
// CNOT ring CNOT(0,1)..CNOT(10,11),CNOT(11,0); wire w <-> bit (11-w).
// Forward index map F: amplitude at i lands at F(i).  (verified: F(0x800)=0x7FF)
__host__ __device__ constexpr int Fmap(int y){
  int s = y ^ (y>>1); s ^= s>>2; s ^= s>>4; s ^= s>>8;
  return (s ^ ((s&1)<<11)) & 0xFFF;
}
// Inverse map G = F^{-1}: new[i] = old[G(i)].   (verified: G(0x7FF)=0x800)
__host__ __device__ constexpr int Gmap(int y){ return (y ^ (y>>1)) ^ ((y&1)*0xC00); }

__device__ __forceinline__ float sgnf(float M, int bitv){
  return __int_as_float(__float_as_int(M) ^ (bitv<<31));
}

// Fused 2x2 complex gate on owned bit J of register-resident state.
template<int J>
__device__ __forceinline__ void gate_on_bit(float2 (&s)[16], const float* __restrict__ u){
  const float u00x=u[0], u00y=u[1], u01x=u[2], u01y=u[3];
  const float u10x=u[4], u10y=u[5], u11x=u[6], u11y=u[7];
#pragma unroll
  for (int k = 0; k < 16; ++k){
    if (k & (1 << J)) continue;
    const int k1 = k | (1 << J);
    const float ax = s[k].x, ay = s[k].y, bx = s[k1].x, by = s[k1].y;
    s[k].x  = u00x*ax - u00y*ay + u01x*bx - u01y*by;
    s[k].y  = u00x*ay + u00y*ax + u01x*by + u01y*bx;
    s[k1].x = u10x*ax - u10y*ay + u11x*bx - u11y*by;
    s[k1].y = u10x*ay + u10y*ax + u11x*by + u11y*bx;
  }
}

// Precompute 24 fused U = Rz*Ry*Rx (layer-major, qubit-minor). Uniform loads
// in qsim stay on the scalar pipe (s_load), so keep this a separate kernel.
__global__ __launch_bounds__(64)
void prep_gates(const float* __restrict__ w, float* __restrict__ U){
  const int t = threadIdx.x;
  if (t >= 24) return;
  const int l = t / 12, q = t % 12;
  const float ax = 0.5f * w[l*36 + q*3 + 0];
  const float ay = 0.5f * w[l*36 + q*3 + 1];
  const float az = 0.5f * w[l*36 + q*3 + 2];
  const float ca = cosf(ax), sa = sinf(ax);
  const float cb = cosf(ay), sb = sinf(ay);
  const float cc = cosf(az), sc = sinf(az);
  const float m00x =  cb*ca, m00y =  sb*sa;
  const float m01x = -sb*ca, m01y = -cb*sa;
  const float m10x =  sb*ca, m10y = -cb*sa;
  const float m11x =  cb*ca, m11y = -sb*sa;
  float* o = U + t*8;
  o[0] = cc*m00x + sc*m00y;  o[1] = cc*m00y - sc*m00x;
  o[2] = cc*m01x + sc*m01y;  o[3] = cc*m01y - sc*m01x;
  o[4] = cc*m10x - sc*m10y;  o[5] = cc*m10y + sc*m10x;
  o[6] = cc*m11x - sc*m11y;  o[7] = cc*m11y + sc*m11x;
}

__global__ __launch_bounds__(256)
void qsim_kernel(const float* __restrict__ x, const float* __restrict__ U,
                 float* __restrict__ out){
  __shared__ float2 st[DIM];          // 32 KB
  float* red = (float*)st;
  const int tid = threadIdx.x;
  const int b   = blockIdx.x;

  // ---- per-sample encoding angles -----------------------------------------
  if (tid < NQ){
    const float a = x[b*NQ + tid] * 1.5707963267948966f;
    red[tid]      = cosf(a);
    red[tid + 16] = sinf(a);
  }
  __syncthreads();
  float cw[NQ], sw[NQ];
#pragma unroll
  for (int w = 0; w < NQ; ++w){ cw[w] = red[w]; sw[w] = red[w + 16]; }
  __syncthreads();

  // ---- precomputed per-pass address bases (phys/F/G all GF(2)-linear) -----
  const int m4    = (tid >> 4) & 1;
  const int baseA = tid ^ ((tid >> 4) & 15);                       // bits 0-7
  const int baseB = (tid & 15) | (m4 << 4) | ((tid >> 4) << 8);
  const int baseC = ((tid & 15) | (tid << 4)) ^ (m4 << 4);
  const int pgt   = physv(Gmap(tid));                              // gather base

  // ---- init product state, ownership A: i = tid | (k<<8) ------------------
  float2 s[16];
  {
    float base = 1.f;
#pragma unroll
    for (int p = 0; p < 8; ++p) base *= ((tid >> p) & 1) ? sw[11-p] : cw[11-p];
#pragma unroll
    for (int k = 0; k < 16; ++k){
      float amp = base;
#pragma unroll
      for (int p = 8; p < 12; ++p) amp *= ((k >> (p-8)) & 1) ? sw[11-p] : cw[11-p];
      s[k] = make_float2(amp, 0.f);
    }
  }

#define WRITE_A  _Pragma("unroll") for (int k = 0; k < 16; ++k) \
    st[(baseA ^ ((k & 1) << 4)) | (k << 8)] = s[k];
#define READ_B   _Pragma("unroll") for (int k = 0; k < 16; ++k) \
    s[k] = st[baseB ^ (17 * k)];
#define WRITE_B  _Pragma("unroll") for (int k = 0; k < 16; ++k) \
    st[baseB ^ (17 * k)] = s[k];
#define READ_C   _Pragma("unroll") for (int k = 0; k < 16; ++k) \
    s[k] = st[baseC ^ k];
#define WRITE_C  _Pragma("unroll") for (int k = 0; k < 16; ++k) \
    st[baseC ^ k] = s[k];
#define READ_GA  _Pragma("unroll") for (int k = 0; k < 16; ++k) \
    s[k] = st[pgt ^ physc(Gmap(k << 8))];

  // ================= layer 0 =================
  // ownership A: reg bit j <-> bit 8+j <-> wire 3-j
  gate_on_bit<0>(s, U + (0*12 + 3)*8);
  gate_on_bit<1>(s, U + (0*12 + 2)*8);
  gate_on_bit<2>(s, U + (0*12 + 1)*8);
  gate_on_bit<3>(s, U + (0*12 + 0)*8);
  WRITE_A;
  __syncthreads();
  READ_B;                              // ownership B: bit j <-> wire 7-j
  gate_on_bit<0>(s, U + (0*12 + 7)*8);
  gate_on_bit<1>(s, U + (0*12 + 6)*8);
  gate_on_bit<2>(s, U + (0*12 + 5)*8);
  gate_on_bit<3>(s, U + (0*12 + 4)*8);
  WRITE_B;                             // same per-thread slot set: no barrier
  __syncthreads();
  READ_C;                              // ownership C: bit j <-> wire 11-j
  gate_on_bit<0>(s, U + (0*12 + 11)*8);
  gate_on_bit<1>(s, U + (0*12 + 10)*8);
  gate_on_bit<2>(s, U + (0*12 +  9)*8);
  gate_on_bit<3>(s, U + (0*12 +  8)*8);
  WRITE_C;
  __syncthreads();

  // ================= layer 1 =================
  READ_GA;                             // layer-0 CNOT ring folded into gather
  gate_on_bit<0>(s, U + (1*12 + 3)*8);
  gate_on_bit<1>(s, U + (1*12 + 2)*8);
  gate_on_bit<2>(s, U + (1*12 + 1)*8);
  gate_on_bit<3>(s, U + (1*12 + 0)*8);
  __syncthreads();                     // scattered gather reads must drain
  WRITE_A;
  __syncthreads();
  READ_B;
  gate_on_bit<0>(s, U + (1*12 + 7)*8);
  gate_on_bit<1>(s, U + (1*12 + 6)*8);
  gate_on_bit<2>(s, U + (1*12 + 5)*8);
  gate_on_bit<3>(s, U + (1*12 + 4)*8);
  WRITE_B;
  __syncthreads();
  READ_C;
  gate_on_bit<0>(s, U + (1*12 + 11)*8);
  gate_on_bit<1>(s, U + (1*12 + 10)*8);
  gate_on_bit<2>(s, U + (1*12 +  9)*8);
  gate_on_bit<3>(s, U + (1*12 +  8)*8);

  // ---- output: layer-1 ring as index map; Walsh butterfly over k ----------
  // j = F(k | tid<<4) = F(k) ^ F(tid<<4).  F(k) for k<16 has bits only at
  // {0..3,11}: sign vectors over k collapse to 5 sums.
  const int ft = Fmap(tid << 4);
  float p2[16];
#pragma unroll
  for (int k = 0; k < 16; ++k) p2[k] = s[k].x*s[k].x + s[k].y*s[k].y;
  float u8[8], v8[8];
#pragma unroll
  for (int l = 0; l < 8; ++l){ u8[l] = p2[l] + p2[l+8]; v8[l] = p2[l] - p2[l+8]; }
  const float T  = ((u8[0]+u8[1])+(u8[2]+u8[3])) + ((u8[4]+u8[5])+(u8[6]+u8[7]));
  const float S3 = ((v8[0]+v8[1])+(v8[2]+v8[3])) + ((v8[4]+v8[5])+(v8[6]+v8[7]));
  float a4[4];
#pragma unroll
  for (int l = 0; l < 4; ++l) a4[l] = v8[l] - v8[l+4];
  const float S23   = (a4[0]+a4[1]) + (a4[2]+a4[3]);
  const float b0 = a4[0]-a4[2], b1 = a4[1]-a4[3];
  const float S123  = b0 + b1;
  const float S0123 = b0 - b1;

  float r[NQ];
  r[0]  = sgnf(S0123, (ft >> 11) & 1);          // wire 0  <-> bit 11 (parity)
#pragma unroll
  for (int w = 1; w <= 7; ++w)                  // wires 1-7 <-> bits 10..4: +T
    r[w] = sgnf(T, (ft >> (11 - w)) & 1);
  r[8]  = sgnf(S3,    (ft >> 3) & 1);
  r[9]  = sgnf(S23,   (ft >> 2) & 1);
  r[10] = sgnf(S123,  (ft >> 1) & 1);
  r[11] = sgnf(S0123,  ft       & 1);

  // ---- block reduction ----------------------------------------------------
#pragma unroll
  for (int off = 32; off; off >>= 1)
#pragma unroll
    for (int w = 0; w < NQ; ++w) r[w] += __shfl_down(r[w], off);
  __syncthreads();                    // all state reads done; reuse LDS
  const int lane = tid & 63, wid = tid >> 6;
  if (lane == 0){
#pragma unroll
    for (int w = 0; w < NQ; ++w) red[wid*NQ + w] = r[w];
  }
  __syncthreads();
  if (tid < NQ)
    out[b*NQ + tid] = red[tid] + red[NQ + tid] + red[2*NQ + tid] + red[3*NQ + tid];
}

extern "C" void kernel_launch(void* const* d_in, const int* in_sizes, int n_in,
                              void* d_out, int out_size, void* d_ws, size_t ws_size,
                              hipStream_t stream){
  const float* x = (const float*)d_in[0];
  const float* w = (const float*)d_in[1];
  float* out = (float*)d_out;
  float* U   = (float*)d_ws;          // 24 gates * 8 floats = 768 B
  const int B = in_sizes[0] / NQ;     // 2048

  prep_gates<<<1, 64, 0, stream>>>(w, U);
  qsim_kernel<<<B, 256, 0, stream>>>(x, U, out);
}

// Round 3
// 90.196 us; speedup vs baseline: 1.3585x; 1.1360x over previous
//
#include <hip/hip_runtime.h>
#include <math.h>

#define NQ 12
#define DIM 4096

#pragma clang fp contract(fast)

// ---- GF(2)-linear index maps ----------------------------------------------
__device__ __forceinline__ int physv(int i){ return i ^ ((i>>4)&15) ^ (((i>>8)&1)<<4); }
__host__ __device__ constexpr int physc(int i){ return i ^ ((i>>4)&15) ^ (((i>>8)&1)<<4); }
// CNOT ring CNOT(0,1)..CNOT(10,11),CNOT(11,0); wire w <-> bit (11-w).
__host__ __device__ constexpr int Fmap(int y){
  int s = y ^ (y>>1); s ^= s>>2; s ^= s>>4; s ^= s>>8;
  return (s ^ ((s&1)<<11)) & 0xFFF;
}
__host__ __device__ constexpr int Gmap(int y){ return (y ^ (y>>1)) ^ ((y&1)*0xC00); }

__device__ __forceinline__ float sgnf(float M, int bitv){
  return __int_as_float(__float_as_int(M) ^ (bitv<<31));
}

// Fused 2x2 complex gate on owned bit J — explicit FMA form (hipcc does not
// contract mul/add chains here; measured r2: ~7 ops/output vs 4 fused).
template<int J>
__device__ __forceinline__ void gate_on_bit(float2 (&s)[16], const float* __restrict__ u){
  const float u00x=u[0], u00y=u[1], u01x=u[2], u01y=u[3];
  const float u10x=u[4], u10y=u[5], u11x=u[6], u11y=u[7];
#pragma unroll
  for (int k = 0; k < 16; ++k){
    if (k & (1 << J)) continue;
    const int k1 = k | (1 << J);
    const float ax = s[k].x, ay = s[k].y, bx = s[k1].x, by = s[k1].y;
    s[k].x  = fmaf(u00x, ax, fmaf(-u00y, ay, fmaf(u01x, bx, -u01y*by)));
    s[k].y  = fmaf(u00x, ay, fmaf( u00y, ax, fmaf(u01x, by,  u01y*bx)));
    s[k1].x = fmaf(u10x, ax, fmaf(-u10y, ay, fmaf(u11x, bx, -u11y*by)));
    s[k1].y = fmaf(u10x, ay, fmaf( u10y, ax, fmaf(u11x, by,  u11y*bx)));
  }
}

// Precompute 24 fused U = Rz*Ry*Rx (layer-major, qubit-minor).
__global__ __launch_bounds__(64)
void prep_gates(const float* __restrict__ w, float* __restrict__ U){
  const int t = threadIdx.x;
  if (t >= 24) return;
  const int l = t / 12, q = t % 12;
  const float ax = 0.5f * w[l*36 + q*3 + 0];
  const float ay = 0.5f * w[l*36 + q*3 + 1];
  const float az = 0.5f * w[l*36 + q*3 + 2];
  const float ca = cosf(ax), sa = sinf(ax);
  const float cb = cosf(ay), sb = sinf(ay);
  const float cc = cosf(az), sc = sinf(az);
  const float m00x =  cb*ca, m00y =  sb*sa;
  const float m01x = -sb*ca, m01y = -cb*sa;
  const float m10x =  sb*ca, m10y = -cb*sa;
  const float m11x =  cb*ca, m11y = -sb*sa;
  float* o = U + t*8;
  o[0] = cc*m00x + sc*m00y;  o[1] = cc*m00y - sc*m00x;
  o[2] = cc*m01x + sc*m01y;  o[3] = cc*m01y - sc*m01x;
  o[4] = cc*m10x - sc*m10y;  o[5] = cc*m10y + sc*m10x;
  o[6] = cc*m11x - sc*m11y;  o[7] = cc*m11y + sc*m11x;
}

__global__ __launch_bounds__(256)
void qsim_kernel(const float* __restrict__ x, const float* __restrict__ U,
                 float* __restrict__ out){
  __shared__ float2 st[DIM];          // 32 KB
  float* red = (float*)st;
  char*  stb = (char*)st;
  const int tid = threadIdx.x;
  const int b   = blockIdx.x;

  // ---- per-sample encoding angles -----------------------------------------
  if (tid < NQ){
    const float a = x[b*NQ + tid] * 1.5707963267948966f;
    red[tid]      = cosf(a);
    red[tid + 16] = sinf(a);
  }
  __syncthreads();
  float cw[NQ], sw[NQ];
#pragma unroll
  for (int w = 0; w < NQ; ++w){ cw[w] = red[w]; sw[w] = red[w + 16]; }
  __syncthreads();

  // ---- per-pass BYTE address bases (phys/F/G all GF(2)-linear) ------------
  const int m4 = (tid >> 4) & 1;
  const int bA = (tid ^ ((tid >> 4) & 15)) << 3;
  const int bB = ((tid & 15) | (m4 << 4) | ((tid >> 4) << 8)) << 3;
  const int bC = (((tid & 15) | (tid << 4)) ^ (m4 << 4)) << 3;
  const int bG = physv(Gmap(tid)) << 3;

  // ---- init product state (hierarchical product tree) ---------------------
  // ownership A: i = tid | (k<<8); tid bit p <-> wire 11-p; k bit j <-> wire 3-j
  float2 s[16];
  {
    const float b01 = ((tid&1)  ? sw[11]:cw[11]) * ((tid&2)  ? sw[10]:cw[10]);
    const float b23 = ((tid&4)  ? sw[9] :cw[9])  * ((tid&8)  ? sw[8] :cw[8]);
    const float b45 = ((tid&16) ? sw[7] :cw[7])  * ((tid&32) ? sw[6] :cw[6]);
    const float b67 = ((tid&64) ? sw[5] :cw[5])  * ((tid&128)? sw[4] :cw[4]);
    const float base = (b01*b23)*(b45*b67);
    float m01[4], m23[4];
#pragma unroll
    for (int a = 0; a < 4; ++a){
      m01[a] = ((a&1)?sw[3]:cw[3]) * ((a&2)?sw[2]:cw[2]);
      m23[a] = ((a&1)?sw[1]:cw[1]) * ((a&2)?sw[0]:cw[0]);
    }
#pragma unroll
    for (int k = 0; k < 16; ++k)
      s[k] = make_float2(base * (m01[k&3] * m23[k>>2]), 0.f);
  }

  // A-pattern: k<<11 disjoint from base -> folds into ds offset immediate.
#define WRITE_A  _Pragma("unroll") for (int k = 0; k < 16; ++k) \
    *(float2*)(stb + ((bA ^ ((k & 1) << 7)) | (k << 11))) = s[k];
#define READ_B   _Pragma("unroll") for (int k = 0; k < 16; ++k) \
    s[k] = *(const float2*)(stb + (bB ^ (136 * k)));
#define WRITE_B  _Pragma("unroll") for (int k = 0; k < 16; ++k) \
    *(float2*)(stb + (bB ^ (136 * k))) = s[k];
#define READ_C   _Pragma("unroll") for (int k = 0; k < 16; ++k) \
    s[k] = *(const float2*)(stb + (bC ^ (k << 3)));
#define WRITE_C  _Pragma("unroll") for (int k = 0; k < 16; ++k) \
    *(float2*)(stb + (bC ^ (k << 3))) = s[k];
#define READ_GA  _Pragma("unroll") for (int k = 0; k < 16; ++k) \
    s[k] = *(const float2*)(stb + (bG ^ (physc(Gmap(k << 8)) << 3)));

  // ================= layer 0 =================
  gate_on_bit<0>(s, U + (0*12 + 3)*8);   // ownership A: reg bit j <-> wire 3-j
  gate_on_bit<1>(s, U + (0*12 + 2)*8);
  gate_on_bit<2>(s, U + (0*12 + 1)*8);
  gate_on_bit<3>(s, U + (0*12 + 0)*8);
  WRITE_A;
  __syncthreads();
  READ_B;                                // ownership B: reg bit j <-> wire 7-j
  gate_on_bit<0>(s, U + (0*12 + 7)*8);
  gate_on_bit<1>(s, U + (0*12 + 6)*8);
  gate_on_bit<2>(s, U + (0*12 + 5)*8);
  gate_on_bit<3>(s, U + (0*12 + 4)*8);
  WRITE_B;                               // same slots just read: no barrier
  __syncthreads();
  READ_C;                                // ownership C: reg bit j <-> wire 11-j
  gate_on_bit<0>(s, U + (0*12 + 11)*8);
  gate_on_bit<1>(s, U + (0*12 + 10)*8);
  gate_on_bit<2>(s, U + (0*12 +  9)*8);
  gate_on_bit<3>(s, U + (0*12 +  8)*8);
  WRITE_C;
  __syncthreads();

  // ================= layer 1 =================
  READ_GA;                               // layer-0 CNOT ring folded into gather
  gate_on_bit<0>(s, U + (1*12 + 3)*8);
  gate_on_bit<1>(s, U + (1*12 + 2)*8);
  gate_on_bit<2>(s, U + (1*12 + 1)*8);
  gate_on_bit<3>(s, U + (1*12 + 0)*8);
  __syncthreads();                       // scattered gather reads must drain
  WRITE_A;
  __syncthreads();
  READ_B;
  gate_on_bit<0>(s, U + (1*12 + 7)*8);
  gate_on_bit<1>(s, U + (1*12 + 6)*8);
  gate_on_bit<2>(s, U + (1*12 + 5)*8);
  gate_on_bit<3>(s, U + (1*12 + 4)*8);
  WRITE_B;
  __syncthreads();
  READ_C;
  gate_on_bit<0>(s, U + (1*12 + 11)*8);
  gate_on_bit<1>(s, U + (1*12 + 10)*8);
  gate_on_bit<2>(s, U + (1*12 +  9)*8);
  gate_on_bit<3>(s, U + (1*12 +  8)*8);

  // ---- output: layer-1 ring as index map; Walsh butterfly over k ----------
  const int ft = Fmap(tid << 4);
  float p2[16];
#pragma unroll
  for (int k = 0; k < 16; ++k) p2[k] = fmaf(s[k].x, s[k].x, s[k].y*s[k].y);
  float u8[8], v8[8];
#pragma unroll
  for (int l = 0; l < 8; ++l){ u8[l] = p2[l] + p2[l+8]; v8[l] = p2[l] - p2[l+8]; }
  const float T  = ((u8[0]+u8[1])+(u8[2]+u8[3])) + ((u8[4]+u8[5])+(u8[6]+u8[7]));
  const float S3 = ((v8[0]+v8[1])+(v8[2]+v8[3])) + ((v8[4]+v8[5])+(v8[6]+v8[7]));
  float a4[4];
#pragma unroll
  for (int l = 0; l < 4; ++l) a4[l] = v8[l] - v8[l+4];
  const float S23   = (a4[0]+a4[1]) + (a4[2]+a4[3]);
  const float b0 = a4[0]-a4[2], b1 = a4[1]-a4[3];
  const float S123  = b0 + b1;
  const float S0123 = b0 - b1;

  float r[NQ];
  r[0]  = sgnf(S0123, (ft >> 11) & 1);
#pragma unroll
  for (int w = 1; w <= 7; ++w)
    r[w] = sgnf(T, (ft >> (11 - w)) & 1);
  r[8]  = sgnf(S3,    (ft >> 3) & 1);
  r[9]  = sgnf(S23,   (ft >> 2) & 1);
  r[10] = sgnf(S123,  (ft >> 1) & 1);
  r[11] = sgnf(S0123,  ft       & 1);

  // ---- block reduction ----------------------------------------------------
#pragma unroll
  for (int off = 32; off; off >>= 1)
#pragma unroll
    for (int w = 0; w < NQ; ++w) r[w] += __shfl_down(r[w], off);
  __syncthreads();
  const int lane = tid & 63, wid = tid >> 6;
  if (lane == 0){
#pragma unroll
    for (int w = 0; w < NQ; ++w) red[wid*NQ + w] = r[w];
  }
  __syncthreads();
  if (tid < NQ)
    out[b*NQ + tid] = red[tid] + red[NQ + tid] + red[2*NQ + tid] + red[3*NQ + tid];
}

extern "C" void kernel_launch(void* const* d_in, const int* in_sizes, int n_in,
                              void* d_out, int out_size, void* d_ws, size_t ws_size,
                              hipStream_t stream){
  const float* x = (const float*)d_in[0];
  const float* w = (const float*)d_in[1];
  float* out = (float*)d_out;
  float* U   = (float*)d_ws;          // 24 gates * 8 floats = 768 B
  const int B = in_sizes[0] / NQ;     // 2048

  prep_gates<<<1, 64, 0, stream>>>(w, U);
  qsim_kernel<<<B, 256, 0, stream>>>(x, U, out);
}